// Round 3
// baseline (1434.489 us; speedup 1.0000x reference)
//
#include <hip/hip_runtime.h>

// MHSA with relative position bias (Swin window attention), MI355X gfx950.
// B=2048 windows, N=49 tokens, C=1024, 16 heads x 64. fp16 MFMA, fp32 accum.
// Round 3: GEMM rebuilt as 32-phase pipelined schedule:
//  - 32x32x16 f16 MFMA (ceiling 2495 TF vs 2075 for 16x16x32)
//  - 4-slot LDS rotation (4x16KB A + 4x16KB B = 128 KiB), K-half = 32 cols
//  - fragment reads for phase p+1 issued BEFORE phase p's MFMA cluster
//    (double-buffered registers) -> LDS reads hide under MFMA
//  - one barrier per phase; lgkmcnt(0)+vmcnt(8) before it make all
//    cross-wave orderings provable (stage@P landed by vmcnt@P+2, read@P+3)

typedef _Float16 f16;
typedef _Float16 f16x8 __attribute__((ext_vector_type(8)));
typedef _Float16 f16x4 __attribute__((ext_vector_type(4)));
typedef float f32x4 __attribute__((ext_vector_type(4)));
typedef float f32x16 __attribute__((ext_vector_type(16)));

#define G1P(p) ((const __attribute__((address_space(1))) unsigned int*)(p))
#define L3P(p) ((__attribute__((address_space(3))) unsigned int*)(p))

static const size_t MROW_MAX = 100351;   // clamp for padded rows 49..63 (attn)

// ---------------- fp32 -> fp16 convert (vec4) ----------------
__global__ void cvt_kernel(const float* __restrict__ in, f16* __restrict__ out, int n4) {
  int i = blockIdx.x * blockDim.x + threadIdx.x;
  int stride = gridDim.x * blockDim.x;
  const float4* in4 = (const float4*)in;
  f16x4* out4 = (f16x4*)out;
  for (; i < n4; i += stride) {
    float4 v = in4[i];
    f16x4 o = { (f16)v.x, (f16)v.y, (f16)v.z, (f16)v.w };
    out4[i] = o;
  }
}

// ---------------- bias table: bias_all[h][64][64], mask folded in ----------------
__global__ void bias_kernel(const float* __restrict__ rpb, float* __restrict__ bias_all) {
  int h = blockIdx.x;
  for (int e = threadIdx.x; e < 4096; e += blockDim.x) {
    int n = e >> 6, m = e & 63;
    float v = -1e30f;
    if (n < 49 && m < 49) {
      int in_ = n / 7, jn = n % 7, im = m / 7, jm = m % 7;
      v = rpb[h * 169 + (im - in_ + 6) * 13 + (jm - jn + 6)];
    }
    bias_all[h * 4096 + e] = v;
  }
}

// ---------------- 256x256 pipelined GEMM: C[M,N] = A[M,K=1024] @ B[N,K]^T + bias ----
#define WVM(N) asm volatile("s_waitcnt vmcnt(" #N ")" ::: "memory")
#define WLG    asm volatile("s_waitcnt lgkmcnt(0)" ::: "memory")
#define SB     __builtin_amdgcn_s_barrier()
#define SCB    __builtin_amdgcn_sched_barrier(0)
#define MF(a, b, c) __builtin_amdgcn_mfma_f32_32x32x16_f16(a, b, c, 0, 0, 0)

// stage one K-half pair (A 16KB + B 16KB); per wave: 2 A-slots + 2 B-slots of 1KB
#define STG(CE, SLOT)                                                                       \
  {                                                                                         \
    const f16* ga_ = Ap + arow_g + (CE) + sce;                                              \
    __builtin_amdgcn_global_load_lds(G1P(ga_), L3P(lds + (SLOT) * 16384 + wid * 2048), 16, 0, 0); \
    __builtin_amdgcn_global_load_lds(G1P(ga_ + 16 * 1024), L3P(lds + (SLOT) * 16384 + wid * 2048 + 1024), 16, 0, 0); \
    const f16* gb_ = Bp + brow_g + (CE) + sce;                                              \
    __builtin_amdgcn_global_load_lds(G1P(gb_), L3P(lds + 65536 + (SLOT) * 16384 + wid * 2048), 16, 0, 0); \
    __builtin_amdgcn_global_load_lds(G1P(gb_ + 16 * 1024), L3P(lds + 65536 + (SLOT) * 16384 + wid * 2048 + 1024), 16, 0, 0); \
  }

// frag reads for one K-half: 8 A-frags (4 rowgrp x 2 kk) + 4 B-frags (2 colgrp x 2 kk)
#define READS(AF, BF, RSLOT)                                                                \
  {                                                                                         \
    const char* ab_ = lds + (RSLOT) * 16384 + arowb;                                        \
    AF[0] = *(const f16x8*)(ab_ + 0 * 2048 + ck0); AF[1] = *(const f16x8*)(ab_ + 0 * 2048 + ck1); \
    AF[2] = *(const f16x8*)(ab_ + 1 * 2048 + ck0); AF[3] = *(const f16x8*)(ab_ + 1 * 2048 + ck1); \
    AF[4] = *(const f16x8*)(ab_ + 2 * 2048 + ck0); AF[5] = *(const f16x8*)(ab_ + 2 * 2048 + ck1); \
    AF[6] = *(const f16x8*)(ab_ + 3 * 2048 + ck0); AF[7] = *(const f16x8*)(ab_ + 3 * 2048 + ck1); \
    const char* bb_ = lds + 65536 + (RSLOT) * 16384 + browb;                                \
    BF[0] = *(const f16x8*)(bb_ + 0 * 2048 + ck0); BF[1] = *(const f16x8*)(bb_ + 0 * 2048 + ck1); \
    BF[2] = *(const f16x8*)(bb_ + 1 * 2048 + ck0); BF[3] = *(const f16x8*)(bb_ + 1 * 2048 + ck1); \
  }

// 16 MFMAs: kk0 cluster then kk1 (acc dep distance 8)
#define MFMAS(AF, BF)                                                                       \
  __builtin_amdgcn_s_setprio(1);                                                            \
  acc[0][0] = MF(AF[0], BF[0], acc[0][0]); acc[1][0] = MF(AF[2], BF[0], acc[1][0]);         \
  acc[2][0] = MF(AF[4], BF[0], acc[2][0]); acc[3][0] = MF(AF[6], BF[0], acc[3][0]);         \
  acc[0][1] = MF(AF[0], BF[2], acc[0][1]); acc[1][1] = MF(AF[2], BF[2], acc[1][1]);         \
  acc[2][1] = MF(AF[4], BF[2], acc[2][1]); acc[3][1] = MF(AF[6], BF[2], acc[3][1]);         \
  acc[0][0] = MF(AF[1], BF[1], acc[0][0]); acc[1][0] = MF(AF[3], BF[1], acc[1][0]);         \
  acc[2][0] = MF(AF[5], BF[1], acc[2][0]); acc[3][0] = MF(AF[7], BF[1], acc[3][0]);         \
  acc[0][1] = MF(AF[1], BF[3], acc[0][1]); acc[1][1] = MF(AF[3], BF[3], acc[1][1]);         \
  acc[2][1] = MF(AF[5], BF[3], acc[2][1]); acc[3][1] = MF(AF[7], BF[3], acc[3][1]);         \
  __builtin_amdgcn_s_setprio(0);

template <typename OutT>
__global__ __launch_bounds__(512, 2)
void gemm256(const f16* __restrict__ Ap, const f16* __restrict__ Bp,
             const float* __restrict__ bias, OutT* __restrict__ C,
             int N, int ntiles_n) {
  __shared__ char lds[131072];  // A slots 0..3 at 0; B slots 0..3 at 65536
  const int tid = threadIdx.x;
  const int wid = tid >> 6, ln = tid & 63;
  const int l31 = ln & 31, l5 = ln >> 5;
  const int wm = wid >> 2, wn = wid & 3;
  // swizzle lane constants
  const int swzg = (l31 >> 1) & 3;
  const int ck0 = ((0 * 2 + l5) ^ swzg) << 4;   // kk=0 chunk byte offset
  const int ck1 = ((1 * 2 + l5) ^ swzg) << 4;   // kk=1
  const int srow = ln >> 2;
  const int sce = (((ln & 3) ^ ((ln >> 3) & 3)) << 3);  // staging source elem offset
  const int arowb = (wm * 128 + l31) * 64;      // A frag base byte (rg stride 2048)
  const int browb = (wn * 64 + l31) * 64;       // B frag base byte (cg stride 2048)

  // XCD-chunked 1D swizzle (grid divisible by 8), n-fastest for A-panel L2 reuse
  const int nblk = gridDim.x;
  const int wg = (blockIdx.x & 7) * (nblk >> 3) + (blockIdx.x >> 3);
  const int bn = wg % ntiles_n, bm = wg / ntiles_n;
  const int m0 = bm * 256, n0 = bn * 256;

  const size_t arow_g = (size_t)(m0 + wid * 32 + srow) * 1024;
  const size_t brow_g = (size_t)(n0 + wid * 32 + srow) * 1024;

  f32x16 acc[4][2];
#pragma unroll
  for (int i = 0; i < 4; ++i)
#pragma unroll
    for (int j = 0; j < 2; ++j)
      acc[i][j] = (f32x16){0.f, 0.f, 0.f, 0.f, 0.f, 0.f, 0.f, 0.f,
                           0.f, 0.f, 0.f, 0.f, 0.f, 0.f, 0.f, 0.f};
  f16x8 af0[8], af1[8], bf0[4], bf1[4];

  // prologue: stage halves 0..3 into slots 0..3; read frags of half 0
  STG(0, 0); STG(32, 1); STG(64, 2); STG(96, 3);
  WVM(8);            // halves 0,1 landed
  SB; SCB;
  READS(af0, bf0, 0);
  WLG;               // frags0 ready (and read complete before staging slot 0 again)
  SB; SCB;

  // main loop: phases 0..27 (compute half p; read half p+1; stage half p+4)
  int ce = 128;      // element column of next staged half
  for (int i = 0; i < 7; ++i) {
    READS(af1, bf1, 1); STG(ce, 0);       SCB; MFMAS(af0, bf0); WLG; WVM(8); SB; SCB;
    READS(af0, bf0, 2); STG(ce + 32, 1);  SCB; MFMAS(af1, bf1); WLG; WVM(8); SB; SCB;
    READS(af1, bf1, 3); STG(ce + 64, 2);  SCB; MFMAS(af0, bf0); WLG; WVM(8); SB; SCB;
    READS(af0, bf0, 0); STG(ce + 96, 3);  SCB; MFMAS(af1, bf1); WLG; WVM(8); SB; SCB;
    ce += 128;
  }
  // drain: phases 28..31
  READS(af1, bf1, 1); SCB; MFMAS(af0, bf0); WLG; WVM(4); SB; SCB;
  READS(af0, bf0, 2); SCB; MFMAS(af1, bf1); WLG; WVM(0); SB; SCB;
  READS(af1, bf1, 3); SCB; MFMAS(af0, bf0); WLG; SB; SCB;
  MFMAS(af1, bf1);

  // epilogue: C row = rg*32 + (r&3) + 8*(r>>2) + 4*l5, col = cg*32 + l31
  float bv[2];
#pragma unroll
  for (int j = 0; j < 2; ++j) bv[j] = bias[n0 + wn * 64 + j * 32 + l31];
#pragma unroll
  for (int rg = 0; rg < 4; ++rg)
#pragma unroll
    for (int cg = 0; cg < 2; ++cg)
#pragma unroll
      for (int r = 0; r < 16; ++r) {
        int grow = m0 + wm * 128 + rg * 32 + (r & 3) + 8 * (r >> 2) + 4 * l5;
        int gcol = n0 + wn * 64 + cg * 32 + l31;
        C[(size_t)grow * N + gcol] = (OutT)(acc[rg][cg][r] + bv[cg]);
      }
}

// ---------------- attention: one wave per (window, head) ----------------
__global__ __launch_bounds__(64)
void attn_kernel(const f16* __restrict__ qkv,        // [MTOT][3072] q|k|v
                 const float* __restrict__ bias_all, // [16][64][64]
                 f16* __restrict__ out) {             // [MTOT][1024]
  __shared__ char lds[24576];  // K:[0,8K)  Vt:[8K,16K)  P:[16K,24K)
  const int bh = blockIdx.x;
  const int b = bh >> 4, h = bh & 15;
  const int ln = threadIdx.x;
  const int l15 = ln & 15, lhi = ln >> 4;
  const size_t base = (size_t)b * 49;

  f16x8 qf[4][2];
#pragma unroll
  for (int t = 0; t < 4; ++t) {
    size_t row = base + t * 16 + l15;
    if (row > MROW_MAX) row = MROW_MAX;
    const f16* qp = qkv + row * 3072 + h * 64 + lhi * 8;
    qf[t][0] = *(const f16x8*)(qp);
    qf[t][1] = *(const f16x8*)(qp + 32);
  }
  {
    int rA = ln >> 3, lc = ln & 7;
#pragma unroll
    for (int c = 0; c < 8; ++c) {
      int r = c * 8 + rA;
      int ce = (lc ^ (r & 7)) << 3;
      size_t row = base + r;
      if (row > MROW_MAX) row = MROW_MAX;
      const f16* g = qkv + row * 3072 + 1024 + h * 64 + ce;
      __builtin_amdgcn_global_load_lds(G1P(g), L3P(lds + c * 1024), 16, 0, 0);
    }
  }
  {
    size_t row = base + ln;
    if (row > MROW_MAX) row = MROW_MAX;
    const f16* vp = qkv + row * 3072 + 2048 + h * 64;
    f16x8 vr[8];
#pragma unroll
    for (int j = 0; j < 8; ++j) vr[j] = *(const f16x8*)(vp + j * 8);
#pragma unroll
    for (int d = 0; d < 64; ++d)
      *(f16*)(lds + 8192 + d * 128 + ((ln * 2) ^ ((d & 7) << 4))) = vr[d >> 3][d & 7];
  }
  __syncthreads();

  f32x4 acc[4][4];
#pragma unroll
  for (int i = 0; i < 4; ++i)
#pragma unroll
    for (int j = 0; j < 4; ++j) acc[i][j] = (f32x4){0.f, 0.f, 0.f, 0.f};
#pragma unroll
  for (int kk = 0; kk < 2; ++kk) {
    f16x8 bf[4];
#pragma unroll
    for (int t = 0; t < 4; ++t) {
      int mr = t * 16 + l15;
      int pb = (kk * 64 + lhi * 16) ^ ((mr & 7) << 4);
      bf[t] = *(const f16x8*)(lds + mr * 128 + pb);
    }
#pragma unroll
    for (int i = 0; i < 4; ++i)
#pragma unroll
      for (int j = 0; j < 4; ++j)
        acc[i][j] = __builtin_amdgcn_mfma_f32_16x16x32_f16(qf[i][kk], bf[j], acc[i][j], 0, 0, 0);
  }

  const float* bb = bias_all + h * 4096;
#pragma unroll
  for (int i = 0; i < 4; ++i) {
#pragma unroll
    for (int r = 0; r < 4; ++r) {
      int n = i * 16 + lhi * 4 + r;
      float lv[4];
#pragma unroll
      for (int j = 0; j < 4; ++j)
        lv[j] = acc[i][j][r] * 0.125f + bb[n * 64 + j * 16 + l15];
      float Mx = fmaxf(fmaxf(lv[0], lv[1]), fmaxf(lv[2], lv[3]));
#pragma unroll
      for (int off = 1; off < 16; off <<= 1) Mx = fmaxf(Mx, __shfl_xor(Mx, off));
      float s = 0.f;
#pragma unroll
      for (int j = 0; j < 4; ++j) { lv[j] = __expf(lv[j] - Mx); s += lv[j]; }
#pragma unroll
      for (int off = 1; off < 16; off <<= 1) s += __shfl_xor(s, off);
      float inv = 1.f / s;
#pragma unroll
      for (int j = 0; j < 4; ++j) {
        int m = j * 16 + l15;
        *(f16*)(lds + 16384 + n * 128 + ((m * 2) ^ ((n & 7) << 4))) = (f16)(lv[j] * inv);
      }
    }
  }
  __syncthreads();

  f32x4 o[4][4];
#pragma unroll
  for (int i = 0; i < 4; ++i)
#pragma unroll
    for (int j = 0; j < 4; ++j) o[i][j] = (f32x4){0.f, 0.f, 0.f, 0.f};
#pragma unroll
  for (int kk = 0; kk < 2; ++kk) {
    f16x8 af[4], bf[4];
#pragma unroll
    for (int t = 0; t < 4; ++t) {
      int nr = t * 16 + l15;
      int pb = (kk * 64 + lhi * 16) ^ ((nr & 7) << 4);
      af[t] = *(const f16x8*)(lds + 16384 + nr * 128 + pb);
      bf[t] = *(const f16x8*)(lds + 8192 + nr * 128 + pb);
    }
#pragma unroll
    for (int i = 0; i < 4; ++i)
#pragma unroll
      for (int j = 0; j < 4; ++j)
        o[i][j] = __builtin_amdgcn_mfma_f32_16x16x32_f16(af[i], bf[j], o[i][j], 0, 0, 0);
  }
#pragma unroll
  for (int i = 0; i < 4; ++i)
#pragma unroll
    for (int j = 0; j < 4; ++j)
#pragma unroll
      for (int r = 0; r < 4; ++r) {
        int n = i * 16 + lhi * 4 + r;
        if (n < 49)
          out[(base + n) * 1024 + h * 64 + j * 16 + l15] = (f16)o[i][j][r];
      }
}

extern "C" void kernel_launch(void* const* d_in, const int* in_sizes, int n_in,
                              void* d_out, int out_size, void* d_ws, size_t ws_size,
                              hipStream_t stream) {
  const float* x      = (const float*)d_in[0];  // [100352][1024]
  const float* qkv_w  = (const float*)d_in[1];  // [3072][1024]
  const float* qkv_b  = (const float*)d_in[2];  // [3072]
  const float* rpb    = (const float*)d_in[3];  // [16][13][13]
  const float* proj_w = (const float*)d_in[4];  // [1024][1024]
  const float* proj_b = (const float*)d_in[5];  // [1024]
  float* out = (float*)d_out;

  char* ws = (char*)d_ws;
  f16*   x16      = (f16*)(ws);                              // 205,520,896
  f16*   wq16     = (f16*)(ws + 205520896);                  //   6,291,456
  f16*   wp16     = (f16*)(ws + 211812352);                  //   2,097,152
  f16*   qkv16    = (f16*)(ws + 213909504);                  // 616,562,688
  f16*   attn16   = (f16*)(ws + 830472192);                  // 205,520,896
  float* bias_all = (float*)(ws + 1035993088);               //     262,144

  cvt_kernel<<<2048, 256, 0, stream>>>(x, x16, 102760448 / 4);
  cvt_kernel<<<1024, 256, 0, stream>>>(qkv_w, wq16, 3145728 / 4);
  cvt_kernel<<<512, 256, 0, stream>>>(proj_w, wp16, 1048576 / 4);
  bias_kernel<<<16, 64, 0, stream>>>(rpb, bias_all);

  // qkv = x @ qkv_w^T + qkv_b   [100352][3072] fp16   (392 x 12 tiles)
  gemm256<f16><<<4704, 512, 0, stream>>>(x16, wq16, qkv_b, qkv16, 3072, 12);
  // attention per (window, head)
  attn_kernel<<<2048 * 16, 64, 0, stream>>>(qkv16, bias_all, attn16);
  // out = attn @ proj_w^T + proj_b   [100352][1024] fp32  (392 x 4 tiles)
  gemm256<float><<<1568, 512, 0, stream>>>(attn16, wp16, proj_b, out, 1024, 4);
}

// Round 4
// 1430.952 us; speedup vs baseline: 1.0025x; 1.0025x over previous
//
#include <hip/hip_runtime.h>

// MHSA with relative position bias (Swin window attention), MI355X gfx950.
// B=2048 windows, N=49 tokens, C=1024, 16 heads x 64. fp16 MFMA, fp32 accum.
// Round 4: R3 pipeline kept; LDS chunk swizzle fixed to be bank-conflict-free
// for b128 reads under the {quad i, quad i+32} co-group model:
//   swz(row) = ((row>>1)&1)<<1 | ((row>>2)&1)   (was (row>>1)&3 -> 2-way conflict)

typedef _Float16 f16;
typedef _Float16 f16x8 __attribute__((ext_vector_type(8)));
typedef _Float16 f16x4 __attribute__((ext_vector_type(4)));
typedef float f32x4 __attribute__((ext_vector_type(4)));
typedef float f32x16 __attribute__((ext_vector_type(16)));

#define G1P(p) ((const __attribute__((address_space(1))) unsigned int*)(p))
#define L3P(p) ((__attribute__((address_space(3))) unsigned int*)(p))

static const size_t MROW_MAX = 100351;   // clamp for padded rows 49..63 (attn)

// ---------------- fp32 -> fp16 convert (vec4) ----------------
__global__ void cvt_kernel(const float* __restrict__ in, f16* __restrict__ out, int n4) {
  int i = blockIdx.x * blockDim.x + threadIdx.x;
  int stride = gridDim.x * blockDim.x;
  const float4* in4 = (const float4*)in;
  f16x4* out4 = (f16x4*)out;
  for (; i < n4; i += stride) {
    float4 v = in4[i];
    f16x4 o = { (f16)v.x, (f16)v.y, (f16)v.z, (f16)v.w };
    out4[i] = o;
  }
}

// ---------------- bias table: bias_all[h][64][64], mask folded in ----------------
__global__ void bias_kernel(const float* __restrict__ rpb, float* __restrict__ bias_all) {
  int h = blockIdx.x;
  for (int e = threadIdx.x; e < 4096; e += blockDim.x) {
    int n = e >> 6, m = e & 63;
    float v = -1e30f;
    if (n < 49 && m < 49) {
      int in_ = n / 7, jn = n % 7, im = m / 7, jm = m % 7;
      v = rpb[h * 169 + (im - in_ + 6) * 13 + (jm - jn + 6)];
    }
    bias_all[h * 4096 + e] = v;
  }
}

// ---------------- 256x256 pipelined GEMM: C[M,N] = A[M,K=1024] @ B[N,K]^T + bias ----
#define WVM(N) asm volatile("s_waitcnt vmcnt(" #N ")" ::: "memory")
#define WLG    asm volatile("s_waitcnt lgkmcnt(0)" ::: "memory")
#define SB     __builtin_amdgcn_s_barrier()
#define SCB    __builtin_amdgcn_sched_barrier(0)
#define MF(a, b, c) __builtin_amdgcn_mfma_f32_32x32x16_f16(a, b, c, 0, 0, 0)

// stage one K-half pair (A 16KB + B 16KB); per wave: 2 A-slots + 2 B-slots of 1KB
#define STG(CE, SLOT)                                                                       \
  {                                                                                         \
    const f16* ga_ = Ap + arow_g + (CE) + sce;                                              \
    __builtin_amdgcn_global_load_lds(G1P(ga_), L3P(lds + (SLOT) * 16384 + wid * 2048), 16, 0, 0); \
    __builtin_amdgcn_global_load_lds(G1P(ga_ + 16 * 1024), L3P(lds + (SLOT) * 16384 + wid * 2048 + 1024), 16, 0, 0); \
    const f16* gb_ = Bp + brow_g + (CE) + sce;                                              \
    __builtin_amdgcn_global_load_lds(G1P(gb_), L3P(lds + 65536 + (SLOT) * 16384 + wid * 2048), 16, 0, 0); \
    __builtin_amdgcn_global_load_lds(G1P(gb_ + 16 * 1024), L3P(lds + 65536 + (SLOT) * 16384 + wid * 2048 + 1024), 16, 0, 0); \
  }

// frag reads for one K-half: 8 A-frags (4 rowgrp x 2 kk) + 4 B-frags (2 colgrp x 2 kk)
#define READS(AF, BF, RSLOT)                                                                \
  {                                                                                         \
    const char* ab_ = lds + (RSLOT) * 16384 + arowb;                                        \
    AF[0] = *(const f16x8*)(ab_ + 0 * 2048 + ck0); AF[1] = *(const f16x8*)(ab_ + 0 * 2048 + ck1); \
    AF[2] = *(const f16x8*)(ab_ + 1 * 2048 + ck0); AF[3] = *(const f16x8*)(ab_ + 1 * 2048 + ck1); \
    AF[4] = *(const f16x8*)(ab_ + 2 * 2048 + ck0); AF[5] = *(const f16x8*)(ab_ + 2 * 2048 + ck1); \
    AF[6] = *(const f16x8*)(ab_ + 3 * 2048 + ck0); AF[7] = *(const f16x8*)(ab_ + 3 * 2048 + ck1); \
    const char* bb_ = lds + 65536 + (RSLOT) * 16384 + browb;                                \
    BF[0] = *(const f16x8*)(bb_ + 0 * 2048 + ck0); BF[1] = *(const f16x8*)(bb_ + 0 * 2048 + ck1); \
    BF[2] = *(const f16x8*)(bb_ + 1 * 2048 + ck0); BF[3] = *(const f16x8*)(bb_ + 1 * 2048 + ck1); \
  }

// 16 MFMAs: kk0 cluster then kk1 (acc dep distance 8)
#define MFMAS(AF, BF)                                                                       \
  __builtin_amdgcn_s_setprio(1);                                                            \
  acc[0][0] = MF(AF[0], BF[0], acc[0][0]); acc[1][0] = MF(AF[2], BF[0], acc[1][0]);         \
  acc[2][0] = MF(AF[4], BF[0], acc[2][0]); acc[3][0] = MF(AF[6], BF[0], acc[3][0]);         \
  acc[0][1] = MF(AF[0], BF[2], acc[0][1]); acc[1][1] = MF(AF[2], BF[2], acc[1][1]);         \
  acc[2][1] = MF(AF[4], BF[2], acc[2][1]); acc[3][1] = MF(AF[6], BF[2], acc[3][1]);         \
  acc[0][0] = MF(AF[1], BF[1], acc[0][0]); acc[1][0] = MF(AF[3], BF[1], acc[1][0]);         \
  acc[2][0] = MF(AF[5], BF[1], acc[2][0]); acc[3][0] = MF(AF[7], BF[1], acc[3][0]);         \
  acc[0][1] = MF(AF[1], BF[3], acc[0][1]); acc[1][1] = MF(AF[3], BF[3], acc[1][1]);         \
  acc[2][1] = MF(AF[5], BF[3], acc[2][1]); acc[3][1] = MF(AF[7], BF[3], acc[3][1]);         \
  __builtin_amdgcn_s_setprio(0);

template <typename OutT>
__global__ __launch_bounds__(512, 2)
void gemm256(const f16* __restrict__ Ap, const f16* __restrict__ Bp,
             const float* __restrict__ bias, OutT* __restrict__ C,
             int N, int ntiles_n) {
  __shared__ char lds[131072];  // A slots 0..3 at 0; B slots 0..3 at 65536
  const int tid = threadIdx.x;
  const int wid = tid >> 6, ln = tid & 63;
  const int l31 = ln & 31, l5 = ln >> 5;
  const int wm = wid >> 2, wn = wid & 3;
  // swizzle lane constants: swz(row) = ((row>>1)&1)<<1 | ((row>>2)&1), period 8 rows
  const int swzg = (((l31 >> 1) & 1) << 1) | ((l31 >> 2) & 1);
  const int ck0 = ((0 + l5) ^ swzg) << 4;       // kk=0 phys chunk byte offset
  const int ck1 = ((2 + l5) ^ swzg) << 4;       // kk=1
  const int srow = ln >> 2;
  const int sce = (((ln & 3) ^ ((((ln >> 3) & 1) << 1) | ((ln >> 4) & 1))) << 3);  // staging src elem offset
  const int arowb = (wm * 128 + l31) * 64;      // A frag base byte (rg stride 2048)
  const int browb = (wn * 64 + l31) * 64;       // B frag base byte (cg stride 2048)

  // XCD-chunked 1D swizzle (grid divisible by 8), n-fastest for A-panel L2 reuse
  const int nblk = gridDim.x;
  const int wg = (blockIdx.x & 7) * (nblk >> 3) + (blockIdx.x >> 3);
  const int bn = wg % ntiles_n, bm = wg / ntiles_n;
  const int m0 = bm * 256, n0 = bn * 256;

  const size_t arow_g = (size_t)(m0 + wid * 32 + srow) * 1024;
  const size_t brow_g = (size_t)(n0 + wid * 32 + srow) * 1024;

  f32x16 acc[4][2];
#pragma unroll
  for (int i = 0; i < 4; ++i)
#pragma unroll
    for (int j = 0; j < 2; ++j)
      acc[i][j] = (f32x16){0.f, 0.f, 0.f, 0.f, 0.f, 0.f, 0.f, 0.f,
                           0.f, 0.f, 0.f, 0.f, 0.f, 0.f, 0.f, 0.f};
  f16x8 af0[8], af1[8], bf0[4], bf1[4];

  // prologue: stage halves 0..3 into slots 0..3; read frags of half 0
  STG(0, 0); STG(32, 1); STG(64, 2); STG(96, 3);
  WVM(8);            // halves 0,1 landed
  SB; SCB;
  READS(af0, bf0, 0);
  WLG;               // frags0 ready (and read complete before staging slot 0 again)
  SB; SCB;

  // main loop: phases 0..27 (compute half p; read half p+1; stage half p+4)
  int ce = 128;      // element column of next staged half
  for (int i = 0; i < 7; ++i) {
    READS(af1, bf1, 1); STG(ce, 0);       SCB; MFMAS(af0, bf0); WLG; WVM(8); SB; SCB;
    READS(af0, bf0, 2); STG(ce + 32, 1);  SCB; MFMAS(af1, bf1); WLG; WVM(8); SB; SCB;
    READS(af1, bf1, 3); STG(ce + 64, 2);  SCB; MFMAS(af0, bf0); WLG; WVM(8); SB; SCB;
    READS(af0, bf0, 0); STG(ce + 96, 3);  SCB; MFMAS(af1, bf1); WLG; WVM(8); SB; SCB;
    ce += 128;
  }
  // drain: phases 28..31
  READS(af1, bf1, 1); SCB; MFMAS(af0, bf0); WLG; WVM(4); SB; SCB;
  READS(af0, bf0, 2); SCB; MFMAS(af1, bf1); WLG; WVM(0); SB; SCB;
  READS(af1, bf1, 3); SCB; MFMAS(af0, bf0); WLG; SB; SCB;
  MFMAS(af1, bf1);

  // epilogue: C row = rg*32 + (r&3) + 8*(r>>2) + 4*l5, col = cg*32 + l31
  float bv[2];
#pragma unroll
  for (int j = 0; j < 2; ++j) bv[j] = bias[n0 + wn * 64 + j * 32 + l31];
#pragma unroll
  for (int rg = 0; rg < 4; ++rg)
#pragma unroll
    for (int cg = 0; cg < 2; ++cg)
#pragma unroll
      for (int r = 0; r < 16; ++r) {
        int grow = m0 + wm * 128 + rg * 32 + (r & 3) + 8 * (r >> 2) + 4 * l5;
        int gcol = n0 + wn * 64 + cg * 32 + l31;
        C[(size_t)grow * N + gcol] = (OutT)(acc[rg][cg][r] + bv[cg]);
      }
}

// ---------------- attention: one wave per (window, head) ----------------
__global__ __launch_bounds__(64)
void attn_kernel(const f16* __restrict__ qkv,        // [MTOT][3072] q|k|v
                 const float* __restrict__ bias_all, // [16][64][64]
                 f16* __restrict__ out) {             // [MTOT][1024]
  __shared__ char lds[24576];  // K:[0,8K)  Vt:[8K,16K)  P:[16K,24K)
  const int bh = blockIdx.x;
  const int b = bh >> 4, h = bh & 15;
  const int ln = threadIdx.x;
  const int l15 = ln & 15, lhi = ln >> 4;
  const size_t base = (size_t)b * 49;

  f16x8 qf[4][2];
#pragma unroll
  for (int t = 0; t < 4; ++t) {
    size_t row = base + t * 16 + l15;
    if (row > MROW_MAX) row = MROW_MAX;
    const f16* qp = qkv + row * 3072 + h * 64 + lhi * 8;
    qf[t][0] = *(const f16x8*)(qp);
    qf[t][1] = *(const f16x8*)(qp + 32);
  }
  {
    int rA = ln >> 3, lc = ln & 7;
#pragma unroll
    for (int c = 0; c < 8; ++c) {
      int r = c * 8 + rA;
      int ce = (lc ^ (r & 7)) << 3;
      size_t row = base + r;
      if (row > MROW_MAX) row = MROW_MAX;
      const f16* g = qkv + row * 3072 + 1024 + h * 64 + ce;
      __builtin_amdgcn_global_load_lds(G1P(g), L3P(lds + c * 1024), 16, 0, 0);
    }
  }
  {
    size_t row = base + ln;
    if (row > MROW_MAX) row = MROW_MAX;
    const f16* vp = qkv + row * 3072 + 2048 + h * 64;
    f16x8 vr[8];
#pragma unroll
    for (int j = 0; j < 8; ++j) vr[j] = *(const f16x8*)(vp + j * 8);
#pragma unroll
    for (int d = 0; d < 64; ++d)
      *(f16*)(lds + 8192 + d * 128 + ((ln * 2) ^ ((d & 7) << 4))) = vr[d >> 3][d & 7];
  }
  __syncthreads();

  f32x4 acc[4][4];
#pragma unroll
  for (int i = 0; i < 4; ++i)
#pragma unroll
    for (int j = 0; j < 4; ++j) acc[i][j] = (f32x4){0.f, 0.f, 0.f, 0.f};
#pragma unroll
  for (int kk = 0; kk < 2; ++kk) {
    f16x8 bf[4];
#pragma unroll
    for (int t = 0; t < 4; ++t) {
      int mr = t * 16 + l15;
      int pb = (kk * 64 + lhi * 16) ^ ((mr & 7) << 4);
      bf[t] = *(const f16x8*)(lds + mr * 128 + pb);
    }
#pragma unroll
    for (int i = 0; i < 4; ++i)
#pragma unroll
      for (int j = 0; j < 4; ++j)
        acc[i][j] = __builtin_amdgcn_mfma_f32_16x16x32_f16(qf[i][kk], bf[j], acc[i][j], 0, 0, 0);
  }

  const float* bb = bias_all + h * 4096;
#pragma unroll
  for (int i = 0; i < 4; ++i) {
#pragma unroll
    for (int r = 0; r < 4; ++r) {
      int n = i * 16 + lhi * 4 + r;
      float lv[4];
#pragma unroll
      for (int j = 0; j < 4; ++j)
        lv[j] = acc[i][j][r] * 0.125f + bb[n * 64 + j * 16 + l15];
      float Mx = fmaxf(fmaxf(lv[0], lv[1]), fmaxf(lv[2], lv[3]));
#pragma unroll
      for (int off = 1; off < 16; off <<= 1) Mx = fmaxf(Mx, __shfl_xor(Mx, off));
      float s = 0.f;
#pragma unroll
      for (int j = 0; j < 4; ++j) { lv[j] = __expf(lv[j] - Mx); s += lv[j]; }
#pragma unroll
      for (int off = 1; off < 16; off <<= 1) s += __shfl_xor(s, off);
      float inv = 1.f / s;
#pragma unroll
      for (int j = 0; j < 4; ++j) {
        int m = j * 16 + l15;
        *(f16*)(lds + 16384 + n * 128 + ((m * 2) ^ ((n & 7) << 4))) = (f16)(lv[j] * inv);
      }
    }
  }
  __syncthreads();

  f32x4 o[4][4];
#pragma unroll
  for (int i = 0; i < 4; ++i)
#pragma unroll
    for (int j = 0; j < 4; ++j) o[i][j] = (f32x4){0.f, 0.f, 0.f, 0.f};
#pragma unroll
  for (int kk = 0; kk < 2; ++kk) {
    f16x8 af[4], bf[4];
#pragma unroll
    for (int t = 0; t < 4; ++t) {
      int nr = t * 16 + l15;
      int pb = (kk * 64 + lhi * 16) ^ ((nr & 7) << 4);
      af[t] = *(const f16x8*)(lds + 16384 + nr * 128 + pb);
      bf[t] = *(const f16x8*)(lds + 8192 + nr * 128 + pb);
    }
#pragma unroll
    for (int i = 0; i < 4; ++i)
#pragma unroll
      for (int j = 0; j < 4; ++j)
        o[i][j] = __builtin_amdgcn_mfma_f32_16x16x32_f16(af[i], bf[j], o[i][j], 0, 0, 0);
  }
#pragma unroll
  for (int i = 0; i < 4; ++i)
#pragma unroll
    for (int j = 0; j < 4; ++j)
#pragma unroll
      for (int r = 0; r < 4; ++r) {
        int n = i * 16 + lhi * 4 + r;
        if (n < 49)
          out[(base + n) * 1024 + h * 64 + j * 16 + l15] = (f16)o[i][j][r];
      }
}

extern "C" void kernel_launch(void* const* d_in, const int* in_sizes, int n_in,
                              void* d_out, int out_size, void* d_ws, size_t ws_size,
                              hipStream_t stream) {
  const float* x      = (const float*)d_in[0];  // [100352][1024]
  const float* qkv_w  = (const float*)d_in[1];  // [3072][1024]
  const float* qkv_b  = (const float*)d_in[2];  // [3072]
  const float* rpb    = (const float*)d_in[3];  // [16][13][13]
  const float* proj_w = (const float*)d_in[4];  // [1024][1024]
  const float* proj_b = (const float*)d_in[5];  // [1024]
  float* out = (float*)d_out;

  char* ws = (char*)d_ws;
  f16*   x16      = (f16*)(ws);                              // 205,520,896
  f16*   wq16     = (f16*)(ws + 205520896);                  //   6,291,456
  f16*   wp16     = (f16*)(ws + 211812352);                  //   2,097,152
  f16*   qkv16    = (f16*)(ws + 213909504);                  // 616,562,688
  f16*   attn16   = (f16*)(ws + 830472192);                  // 205,520,896
  float* bias_all = (float*)(ws + 1035993088);               //     262,144

  cvt_kernel<<<2048, 256, 0, stream>>>(x, x16, 102760448 / 4);
  cvt_kernel<<<1024, 256, 0, stream>>>(qkv_w, wq16, 3145728 / 4);
  cvt_kernel<<<512, 256, 0, stream>>>(proj_w, wp16, 1048576 / 4);
  bias_kernel<<<16, 64, 0, stream>>>(rpb, bias_all);

  // qkv = x @ qkv_w^T + qkv_b   [100352][3072] fp16   (392 x 12 tiles)
  gemm256<f16><<<4704, 512, 0, stream>>>(x16, wq16, qkv_b, qkv16, 3072, 12);
  // attention per (window, head)
  attn_kernel<<<2048 * 16, 64, 0, stream>>>(qkv16, bias_all, attn16);
  // out = attn @ proj_w^T + proj_b   [100352][1024] fp32  (392 x 4 tiles)
  gemm256<float><<<1568, 512, 0, stream>>>(attn16, wp16, proj_b, out, 1024, 4);
}